// Round 9
// baseline (275.918 us; speedup 1.0000x reference)
//
#include <hip/hip_runtime.h>

// Problem constants (from reference)
#define NS     4096                 // N_SAMPLES
#define NW     64                   // N_WIDTH
#define NNODES 257                  // N_NODES
#define SW     (NS * NW)            // 262144
#define ROW    (NW * NNODES)        // 16448 floats per sample region
#define ROW4   (ROW / 4)            // 4112 float4 groups per sample region
#define SWN    ((size_t)NS * NW * NNODES)  // 67,371,008
#define NG4    ((size_t)3 * SWN / 4)       // 50,528,256 float4 groups in big arrays

typedef float v4f __attribute__((ext_vector_type(4)));

// Hard-coded Lagrange basis polynomials over nodes [-1,-0.5,0,0.5,1] (verified R4/R6).
// phi: Horner x^4..x^0; dphi pre-scaled by 128 (1/delta_x); ddphi by 16384.
__device__ __constant__ const float P4[5] = { (float)( 2.0/3.0), (float)(-8.0/3.0),  4.0f, (float)(-8.0/3.0), (float)( 2.0/3.0) };
__device__ __constant__ const float P3[5] = { (float)(-2.0/3.0), (float)( 4.0/3.0),  0.0f, (float)(-4.0/3.0), (float)( 2.0/3.0) };
__device__ __constant__ const float P2[5] = { (float)(-1.0/6.0), (float)( 8.0/3.0), -5.0f, (float)( 8.0/3.0), (float)(-1.0/6.0) };
__device__ __constant__ const float P1[5] = { (float)( 1.0/6.0), (float)(-4.0/3.0),  0.0f, (float)( 4.0/3.0), (float)(-1.0/6.0) };
__device__ __constant__ const float P0[5] = { 0.0f, 0.0f, 1.0f, 0.0f, 0.0f };

__device__ __constant__ const float D3[5] = { (float)( 1024.0/3.0), (float)(-4096.0/3.0),  2048.0f, (float)(-4096.0/3.0), (float)(1024.0/3.0) };
__device__ __constant__ const float D2[5] = { -256.0f, 512.0f, 0.0f, -512.0f, 256.0f };
__device__ __constant__ const float D1[5] = { (float)( -128.0/3.0), (float)( 2048.0/3.0), -1280.0f, (float)( 2048.0/3.0), (float)(-128.0/3.0) };
__device__ __constant__ const float D0[5] = { (float)(   64.0/3.0), (float)( -512.0/3.0),     0.0f, (float)(  512.0/3.0), (float)( -64.0/3.0) };

__device__ __constant__ const float E2[5] = { 131072.0f, -524288.0f, 786432.0f, -524288.0f, 131072.0f };
__device__ __constant__ const float E1[5] = { -65536.0f,  131072.0f,      0.0f, -131072.0f,  65536.0f };
__device__ __constant__ const float E0[5] = { (float)(-16384.0/3.0), (float)(262144.0/3.0), -163840.0f, (float)(262144.0/3.0), (float)(-16384.0/3.0) };

// ---------------------------------------------------------------------------
// K_zero: blit clone. Pure sequential zero-fill of the 3 big arrays.
// Grid-stride, bound-checked, no loads, no logic, plain stores, ~8 VGPR.
// ---------------------------------------------------------------------------
__global__ __launch_bounds__(256) void k_zero(float* __restrict__ big)
{
    const v4f z = { 0.0f, 0.0f, 0.0f, 0.0f };
    v4f* p = reinterpret_cast<v4f*>(big);
    const size_t stride = (size_t)4096 * 256;
    for (size_t g = (size_t)blockIdx.x * 256 + threadIdx.x; g < NG4; g += stride)
        p[g] = z;
}

// ---------------------------------------------------------------------------
// K_values: per-sample. Overwrites hit lines (full 64B lines, no RMW),
// computes t/dt/ddt dots, writes delta_x.  Block = sample, 256 threads.
//   threads 0..63  : dot products (and their a=0 line tasks)
//   threads 0..191 : (a = tid>>6, row = tid&63) line task
// ---------------------------------------------------------------------------
__global__ __launch_bounds__(256) void k_values(
    const float* __restrict__ x,
    const float* __restrict__ weight,   // [64, 257]
    float* __restrict__ out)
{
    const int i   = blockIdx.x;
    const int tid = threadIdx.x;

    // ---- per-sample basis (Horner, redundant per thread) ----
    const float xs = 256.0f * x[i];
    float fel = floorf(xs * 0.25f);
    fel = fminf(fmaxf(fel, 0.0f), 63.0f);
    const int   b = (int)fel * 4;                    // first affected node (mult of 4)
    const float t = 0.5f * (xs - (float)b) - 1.0f;

    float p0[5], p1[5], p2[5];
    #pragma unroll
    for (int j = 0; j < 5; ++j) {
        p0[j] = (((P4[j]*t + P3[j])*t + P2[j])*t + P1[j])*t + P0[j];
        p1[j] = ((D3[j]*t + D2[j])*t + D1[j])*t + D0[j];
        p2[j] = (E2[j]*t + E1[j])*t + E0[j];
    }

    // ---- t/dt/ddt dots (threads 0..63) ----
    if (tid < NW) {
        const float* wrow = weight + tid * NNODES + b;
        float s0 = 0.0f, s1 = 0.0f, s2 = 0.0f;
        #pragma unroll
        for (int j = 0; j < 5; ++j) {
            const float w = wrow[j];
            s0 += w * p0[j]; s1 += w * p1[j]; s2 += w * p2[j];
        }
        out[(size_t)i * NW + tid]                  = s0;
        out[SW + (size_t)i * NW + tid]             = s1;
        out[2 * (size_t)SW + (size_t)i * NW + tid] = s2;
    }
    if (i == 0 && tid == 192)
        out[3 * (size_t)SW + 3 * SWN] = 0.0078125f;  // delta_x

    // ---- hit-line writes (threads 0..191) ----
    if (tid < 192) {
        const int a   = tid >> 6;        // 0,1,2
        const int row = tid & 63;

        // select this array's basis values with compile-time j indexing
        float ba[5];
        #pragma unroll
        for (int j = 0; j < 5; ++j)
            ba[j] = (a == 0) ? p0[j] : ((a == 1) ? p1[j] : p2[j]);

        const int m   = row * NNODES + b;   // first nonzero element in region
        const int rho = row & 3;            // == m & 3 (b is a multiple of 4)

        // Verified R6 patterns at group granularity:
        //   group o_m   (p=0): w0[c] = ba[c - rho]      (0 if OOR)
        //   group o_m+1 (p=1): w1[c] = ba[4 + c - rho]  (0 if OOR)
        float w0[4], w1[4];
        #pragma unroll
        for (int c = 0; c < 4; ++c) {
            float v0 = 0.0f, v1 = 0.0f;
            #pragma unroll
            for (int r = 0; r < 4; ++r) {
                if (r <= c) v0 = (rho == r) ? ba[c - r]     : v0;   // j = c-r in [0,3]
                if (r >= c) v1 = (rho == r) ? ba[4 + c - r] : v1;   // j = 4+c-r in [1,4]... and r==c gives 4
            }
            w0[c] = v0; w1[c] = v1;
        }

        const int q  = (m >> 2) & 3;        // position of group o_m within its line
        const int O0 = (m >> 4) << 2;       // first group of the line

        v4f* r4 = reinterpret_cast<v4f*>(
            out + 3 * (size_t)SW + (size_t)a * SWN + (size_t)i * ROW);

        const v4f z  = { 0.0f, 0.0f, 0.0f, 0.0f };
        const v4f W0 = { w0[0], w0[1], w0[2], w0[3] };
        const v4f W1 = { w1[0], w1[1], w1[2], w1[3] };

        // line 0 (always): slots 0..3; hits at s=q and (if q<3) s=q+1
        #pragma unroll
        for (int s = 0; s < 4; ++s) {
            const v4f t1 = (s == q + 1) ? W1 : z;
            const v4f vv = (s == q)     ? W0 : t1;
            r4[O0 + s] = vv;
        }
        // line 1 (only when the pair straddles, q==3): [W1, 0, 0, 0]
        if (q == 3) {
            r4[O0 + 4] = W1;
            r4[O0 + 5] = z;
            r4[O0 + 6] = z;
            r4[O0 + 7] = z;
        }
    }
}

extern "C" void kernel_launch(void* const* d_in, const int* in_sizes, int n_in,
                              void* d_out, int out_size, void* d_ws, size_t ws_size,
                              hipStream_t stream) {
    const float* x      = (const float*)d_in[0];
    const float* weight = (const float*)d_in[1];
    float* out          = (float*)d_out;
    float* big          = out + 3 * (size_t)SW;

    k_zero<<<4096, 256, 0, stream>>>(big);
    k_values<<<NS, 256, 0, stream>>>(x, weight, out);
}

// Round 10
// 155.051 us; speedup vs baseline: 1.7795x; 1.7795x over previous
//
#include <hip/hip_runtime.h>

// Problem constants (from reference)
#define NS     4096                 // N_SAMPLES
#define NW     64                   // N_WIDTH
#define NNODES 257                  // N_NODES
#define SW     (NS * NW)            // 262144
#define ROW    (NW * NNODES)        // 16448 floats per sample region
#define ROW4   (ROW / 4)            // 4112 float4 groups per sample region
#define SWN    ((size_t)NS * NW * NNODES)  // 67,371,008

// Hard-coded Lagrange basis polynomials over nodes [-1,-0.5,0,0.5,1] (verified R4/R6).
// phi: Horner x^4..x^0; dphi pre-scaled by 128 (1/delta_x); ddphi by 16384.
__device__ __constant__ const float P4[5] = { (float)( 2.0/3.0), (float)(-8.0/3.0),  4.0f, (float)(-8.0/3.0), (float)( 2.0/3.0) };
__device__ __constant__ const float P3[5] = { (float)(-2.0/3.0), (float)( 4.0/3.0),  0.0f, (float)(-4.0/3.0), (float)( 2.0/3.0) };
__device__ __constant__ const float P2[5] = { (float)(-1.0/6.0), (float)( 8.0/3.0), -5.0f, (float)( 8.0/3.0), (float)(-1.0/6.0) };
__device__ __constant__ const float P1[5] = { (float)( 1.0/6.0), (float)(-4.0/3.0),  0.0f, (float)( 4.0/3.0), (float)(-1.0/6.0) };
__device__ __constant__ const float P0[5] = { 0.0f, 0.0f, 1.0f, 0.0f, 0.0f };

__device__ __constant__ const float D3[5] = { (float)( 1024.0/3.0), (float)(-4096.0/3.0),  2048.0f, (float)(-4096.0/3.0), (float)(1024.0/3.0) };
__device__ __constant__ const float D2[5] = { -256.0f, 512.0f, 0.0f, -512.0f, 256.0f };
__device__ __constant__ const float D1[5] = { (float)( -128.0/3.0), (float)( 2048.0/3.0), -1280.0f, (float)( 2048.0/3.0), (float)(-128.0/3.0) };
__device__ __constant__ const float D0[5] = { (float)(   64.0/3.0), (float)( -512.0/3.0),     0.0f, (float)(  512.0/3.0), (float)( -64.0/3.0) };

__device__ __constant__ const float E2[5] = { 131072.0f, -524288.0f, 786432.0f, -524288.0f, 131072.0f };
__device__ __constant__ const float E1[5] = { -65536.0f,  131072.0f,      0.0f, -131072.0f,  65536.0f };
__device__ __constant__ const float E0[5] = { (float)(-16384.0/3.0), (float)(262144.0/3.0), -163840.0f, (float)(262144.0/3.0), (float)(-16384.0/3.0) };

__global__ __launch_bounds__(256) void kann_all(
    const float* __restrict__ x,
    const float* __restrict__ weight,   // [64, 257]
    float* __restrict__ out)
{
    const int i   = blockIdx.x;       // sample
    const int tid = threadIdx.x;

    // ---- per-sample basis (Horner, no divides; redundant per thread) ----
    const float xs = 256.0f * x[i];
    float fel = floorf(xs * 0.25f);
    fel = fminf(fmaxf(fel, 0.0f), 63.0f);
    const int   b = (int)fel * 4;                    // first affected node (mult of 4)
    const float t = 0.5f * (xs - (float)b) - 1.0f;   // reference coord in [-1,1]

    float bas[3][5];
    #pragma unroll
    for (int j = 0; j < 5; ++j) {
        bas[0][j] = (((P4[j]*t + P3[j])*t + P2[j])*t + P1[j])*t + P0[j];
        bas[1][j] = ((D3[j]*t + D2[j])*t + D1[j])*t + D0[j];
        bas[2][j] = (E2[j]*t + E1[j])*t + E0[j];
    }

    // ---- t/dt/ddt dot products (threads 0..63) ----
    if (tid < NW) {
        const float* wrow = weight + tid * NNODES + b;
        float s0 = 0.0f, s1 = 0.0f, s2 = 0.0f;
        #pragma unroll
        for (int j = 0; j < 5; ++j) {
            const float w = wrow[j];
            s0 += w * bas[0][j];
            s1 += w * bas[1][j];
            s2 += w * bas[2][j];
        }
        out[(size_t)i * NW + tid]                   = s0;
        out[SW + (size_t)i * NW + tid]              = s1;
        out[2 * (size_t)SW + (size_t)i * NW + tid]  = s2;
    }
    if (i == 0 && tid == 64)
        out[3 * (size_t)SW + 3 * SWN] = 0.0078125f;  // delta_x

    // ---- hit precompute (register-resident; <=2 hits per thread) ----
    // Nonzero float4 groups of the 4-row period: om = 64*rho + g0 + p,
    // component c holds bas[a][4p + c - rho] (zero if out of [0,4]).
    // Thread's group o = tid + 256*n has om = (tid - n) mod 257, so the hit
    // iteration for om=gm is n = (tid - gm) mod 257, valid when n <= 16.
    const int g0 = b >> 2;
    int h0 = -1, h1 = -1;
    float w0v[3][4], w1v[3][4];
    #pragma unroll
    for (int a = 0; a < 3; ++a)
        #pragma unroll
        for (int c = 0; c < 4; ++c) { w0v[a][c] = 0.0f; w1v[a][c] = 0.0f; }

    #pragma unroll
    for (int rho = 0; rho < 4; ++rho) {
        #pragma unroll
        for (int p = 0; p < 2; ++p) {
            const int gm = 64 * rho + g0 + p;
            int d = tid - gm;
            if (d < 0) d += 257;
            if (d < 17) {
                h1 = h0;
                #pragma unroll
                for (int a = 0; a < 3; ++a)
                    #pragma unroll
                    for (int c = 0; c < 4; ++c) w1v[a][c] = w0v[a][c];
                h0 = d;
                #pragma unroll
                for (int a = 0; a < 3; ++a) {
                    #pragma unroll
                    for (int c = 0; c < 4; ++c) {
                        const int j = 4 * p + c - rho;          // compile-time
                        w0v[a][c] = (j >= 0 && j <= 4) ? bas[a][j] : 0.0f;
                    }
                }
            }
        }
    }

    // ---- pure store machine: a-OUTER, n-inner -> each of the 3 regions is
    // written as one sequential 64KB burst (single-stream, blit-shaped).
    // Store count/width identical to R6; only ORDER changed.               ----
    float* big = out + 3 * (size_t)SW + (size_t)i * ROW;
    float4* rr[3];
    rr[0] = reinterpret_cast<float4*>(big);
    rr[1] = reinterpret_cast<float4*>(big + SWN);
    rr[2] = reinterpret_cast<float4*>(big + 2 * SWN);

    #pragma unroll
    for (int a = 0; a < 3; ++a) {
        float4* r = rr[a];
        #pragma unroll
        for (int n = 0; n < 16; ++n) {
            const int o = tid + (n << 8);
            float v[4];
            #pragma unroll
            for (int c = 0; c < 4; ++c) {
                const float t1 = (n == h1) ? w1v[a][c] : 0.0f;
                v[c]           = (n == h0) ? w0v[a][c] : t1;
            }
            r[o] = make_float4(v[0], v[1], v[2], v[3]);
        }
        // tail: groups 4096..4111 (16 of them), threads 0..15
        if (tid < 16) {
            const int n = 16;
            const int o = tid + (n << 8);
            float v[4];
            #pragma unroll
            for (int c = 0; c < 4; ++c) {
                const float t1 = (n == h1) ? w1v[a][c] : 0.0f;
                v[c]           = (n == h0) ? w0v[a][c] : t1;
            }
            r[o] = make_float4(v[0], v[1], v[2], v[3]);
        }
    }
}

extern "C" void kernel_launch(void* const* d_in, const int* in_sizes, int n_in,
                              void* d_out, int out_size, void* d_ws, size_t ws_size,
                              hipStream_t stream) {
    const float* x      = (const float*)d_in[0];
    const float* weight = (const float*)d_in[1];
    float* out          = (float*)d_out;
    kann_all<<<NS, 256, 0, stream>>>(x, weight, out);
}